// Round 3
// baseline (385.007 us; speedup 1.0000x reference)
//
#include <hip/hip_runtime.h>

#define BB 512
#define LL 1024
#define TT 52
#define START_TAG 50   // T-2
#define STOP_TAG  51   // T-1

__device__ __forceinline__ float rl(float v, int i) {
  return __uint_as_float(__builtin_amdgcn_readlane(__float_as_uint(v), (unsigned)i));
}
__device__ __forceinline__ float wave_max(float v) {
#pragma unroll
  for (int off = 32; off; off >>= 1) v = fmaxf(v, __shfl_xor(v, off, 64));
  return v;
}
__device__ __forceinline__ float wave_sum(float v) {
#pragma unroll
  for (int off = 32; off; off >>= 1) v += __shfl_xor(v, off, 64);
  return v;
}
__device__ __forceinline__ int wave_sum_i(int v) {
#pragma unroll
  for (int off = 32; off; off >>= 1) v += __shfl_xor(v, off, 64);
  return v;
}

// 13 groups of 4 state indices — used for both E-register decls and the step.
#define EGROUPS(G)                                                      \
  G(0, 1, 2, 3) G(4, 5, 6, 7) G(8, 9, 10, 11) G(12, 13, 14, 15)        \
  G(16, 17, 18, 19) G(20, 21, 22, 23) G(24, 25, 26, 27)                \
  G(28, 29, 30, 31) G(32, 33, 34, 35) G(36, 37, 38, 39)                \
  G(40, 41, 42, 43) G(44, 45, 46, 47) G(48, 49, 50, 51)

// One wave per batch; lane j = tag state j.  Forward recursion in exp space
// with per-step bias e^-6 and renorm every 8 steps.  E held in 52 NAMED
// scalar registers (an array here goes to scratch — SROA won't split 208B).
__global__ __launch_bounds__(64, 1) void crf_main(
    const float* __restrict__ feats, const float* __restrict__ trans,
    const void* __restrict__ maskp, const int* __restrict__ tags,
    float* __restrict__ res) {
  const int b = blockIdx.x;
  const int lane = threadIdx.x;
  const bool jok = lane < TT;
  const int j = jok ? lane : TT - 1;        // clamp keeps loads in-bounds

  // ---- per-block length from prefix mask (dtype sniffed from content:
  // len>=512 guarantees first elements true; u8->0x01010101, i32->1,1, i64->1,0)
  const unsigned* m32 = (const unsigned*)maskp;
  int s = 0;
  const unsigned v0 = m32[0];
  if (v0 == 0x01010101u) {                  // bool as bytes
    const uint4* mv = (const uint4*)maskp;  // row = 1024 B = 64 uint4
    uint4 x = mv[b * 64 + lane];
    s  = (int)(((x.x & 0x01010101u) * 0x01010101u) >> 24);
    s += (int)(((x.y & 0x01010101u) * 0x01010101u) >> 24);
    s += (int)(((x.z & 0x01010101u) * 0x01010101u) >> 24);
    s += (int)(((x.w & 0x01010101u) * 0x01010101u) >> 24);
  } else if (m32[1] == 0u) {                // int64
    const unsigned long long* m64 = (const unsigned long long*)maskp;
#pragma unroll
    for (int k = 0; k < 16; ++k) s += (int)m64[(size_t)b * LL + k * 64 + lane];
  } else {                                  // int32
    const int* mi = (const int*)maskp;
#pragma unroll
    for (int k = 0; k < 16; ++k) s += mi[b * LL + k * 64 + lane];
  }
  const int len = wave_sum_i(s);            // uniform

  // ---- E column j in 52 named registers
#define EDECL(a, b_, c, d)                                   \
  float E##a  = jok ? __expf(trans[(a)*TT + j]) : 0.f;       \
  float E##b_ = jok ? __expf(trans[(b_)*TT + j]) : 0.f;      \
  float E##c  = jok ? __expf(trans[(c)*TT + j]) : 0.f;       \
  float E##d  = jok ? __expf(trans[(d)*TT + j]) : 0.f;
  EGROUPS(EDECL)

  const float tl = jok ? __expf(trans[j * TT + STOP_TAG]) : 0.f;

  const float* fp = feats + (size_t)b * LL * TT + j;
  float p = __expf(fp[0]) * E50;            // part0 = f0 + trans[START]
  float carry2 = 0.f;                       // log2 of accumulated renorms

#define ESTEP4(a, b_, c, d)                 \
  a0 = fmaf(rl(p, (a)), E##a, a0);          \
  a1 = fmaf(rl(p, (b_)), E##b_, a1);        \
  a2 = fmaf(rl(p, (c)), E##c, a2);          \
  a3 = fmaf(rl(p, (d)), E##d, a3);

#define CRF_STEP(FV)                        \
  {                                         \
    const float eft = __expf((FV)-6.0f);    \
    float a0 = 0.f, a1 = 0.f, a2 = 0.f, a3 = 0.f; \
    EGROUPS(ESTEP4)                         \
    p = ((a0 + a1) + (a2 + a3)) * eft;      \
  }

  const int nsteps = len - 1;               // steps t = 1 .. len-1
  const int nchunk = nsteps >> 3;
  const int ntail = nsteps & 7;

  float fb[8];                              // emissions for current 8 steps
#pragma unroll
  for (int k = 0; k < 8; ++k) fb[k] = fp[(size_t)(1 + k) * TT];  // len>=512

  int tbase = 1;
  for (int c = 0; c < nchunk; ++c) {
    float fn[8];                            // prefetch next chunk (~8 steps ahead)
#pragma unroll
    for (int k = 0; k < 8; ++k) {
      int tt = tbase + 8 + k;
      tt = tt < len ? tt : len - 1;         // clamp: harmless in-bounds load
      fn[k] = fp[(size_t)tt * TT];
    }
#pragma unroll
    for (int k = 0; k < 8; ++k) CRF_STEP(fb[k]);
    const float m = wave_max(p);            // renorm every 8 steps
    carry2 += __log2f(m);
    p *= __builtin_amdgcn_rcpf(m);
#pragma unroll
    for (int k = 0; k < 8; ++k) fb[k] = fn[k];
    tbase += 8;
  }
#pragma unroll
  for (int k = 0; k < 8; ++k)               // tail, statically indexed
    if (k < ntail) CRF_STEP(fb[k]);

  // forward score = log(sum p_i * e^trans[i,STOP]) + renorms + bias payback
  const float sfin = wave_sum(p * tl);
  const float fwd =
      (__log2f(sfin) + carry2) * 0.6931471805599453f + 6.0f * (float)(len - 1);

  // ---- gold score, lane-parallel over time
  const int* tgb = tags + b * LL;
  float g = 0.f;
  for (int base = 0; base < len; base += 64) {
    const int t = base + lane;
    if (t < len) {
      const int tag = tgb[t];
      const int prev = (t == 0) ? START_TAG : tgb[t - 1];
      g += feats[((size_t)b * LL + t) * TT + tag] + trans[prev * TT + tag];
    }
  }
  g = wave_sum(g);

  if (lane == 0) {
    g += trans[tgb[len - 1] * TT + STOP_TAG];
    res[b] = fwd - g;
  }
#undef CRF_STEP
#undef ESTEP4
#undef EDECL
}

__global__ __launch_bounds__(64) void crf_fin(const float* __restrict__ res,
                                              float* __restrict__ out) {
  float s = 0.f;
#pragma unroll
  for (int k = 0; k < 8; ++k) s += res[threadIdx.x + k * 64];
  s = wave_sum(s);
  if (threadIdx.x == 0) out[0] = s * (1.0f / (float)BB);
}

extern "C" void kernel_launch(void* const* d_in, const int* in_sizes, int n_in,
                              void* d_out, int out_size, void* d_ws, size_t ws_size,
                              hipStream_t stream) {
  const float* feats = (const float*)d_in[0];
  const float* trans = (const float*)d_in[1];
  const void* mask   = (const void*)d_in[2];
  const int* tags    = (const int*)d_in[3];

  float* res = (float*)d_ws;                // 512 per-batch results

  crf_main<<<BB, 64, 0, stream>>>(feats, trans, mask, tags, res);
  crf_fin<<<1, 64, 0, stream>>>(res, (float*)d_out);
}

// Round 4
// 370.939 us; speedup vs baseline: 1.0379x; 1.0379x over previous
//
#include <hip/hip_runtime.h>

#define BB 512
#define LL 1024
#define TT 52
#define START_TAG 50   // T-2
#define STOP_TAG  51   // T-1

__device__ __forceinline__ float rl(float v, int i) {
  return __uint_as_float(__builtin_amdgcn_readlane(__float_as_uint(v), (unsigned)i));
}
__device__ __forceinline__ float wave_max(float v) {
#pragma unroll
  for (int off = 32; off; off >>= 1) v = fmaxf(v, __shfl_xor(v, off, 64));
  return v;
}
__device__ __forceinline__ float wave_sum(float v) {
#pragma unroll
  for (int off = 32; off; off >>= 1) v += __shfl_xor(v, off, 64);
  return v;
}
__device__ __forceinline__ int wave_sum_i(int v) {
#pragma unroll
  for (int off = 32; off; off >>= 1) v += __shfl_xor(v, off, 64);
  return v;
}

// 13 groups of 4 state indices — used for E decls, the step, and the pins.
#define EGROUPS(G)                                                      \
  G(0, 1, 2, 3) G(4, 5, 6, 7) G(8, 9, 10, 11) G(12, 13, 14, 15)        \
  G(16, 17, 18, 19) G(20, 21, 22, 23) G(24, 25, 26, 27)                \
  G(28, 29, 30, 31) G(32, 33, 34, 35) G(36, 37, 38, 39)                \
  G(40, 41, 42, 43) G(44, 45, 46, 47) G(48, 49, 50, 51)

// One wave per batch; lane j = tag state j.  Forward recursion in exp space
// with per-step bias e^-6 and renorm every 8 steps.  E held in 52 named
// registers; amdgpu_waves_per_eu(1,1) lifts the VGPR budget to 512 so the
// allocator stops spilling them (VGPR_Count was capped at 48 in R2/R3).
__global__ __launch_bounds__(64)
__attribute__((amdgpu_waves_per_eu(1, 1)))
void crf_main(
    const float* __restrict__ feats, const float* __restrict__ trans,
    const void* __restrict__ maskp, const int* __restrict__ tags,
    float* __restrict__ res) {
  const int b = blockIdx.x;
  const int lane = threadIdx.x;
  const bool jok = lane < TT;
  const int j = jok ? lane : TT - 1;        // clamp keeps loads in-bounds

  // ---- per-block length from prefix mask (dtype sniffed from content:
  // len>=512 guarantees first elements true; u8->0x01010101, i32->1,1, i64->1,0)
  const unsigned* m32 = (const unsigned*)maskp;
  int s = 0;
  const unsigned v0 = m32[0];
  if (v0 == 0x01010101u) {                  // bool as bytes
    const uint4* mv = (const uint4*)maskp;  // row = 1024 B = 64 uint4
    uint4 x = mv[b * 64 + lane];
    s  = (int)(((x.x & 0x01010101u) * 0x01010101u) >> 24);
    s += (int)(((x.y & 0x01010101u) * 0x01010101u) >> 24);
    s += (int)(((x.z & 0x01010101u) * 0x01010101u) >> 24);
    s += (int)(((x.w & 0x01010101u) * 0x01010101u) >> 24);
  } else if (m32[1] == 0u) {                // int64
    const unsigned long long* m64 = (const unsigned long long*)maskp;
#pragma unroll
    for (int k = 0; k < 16; ++k) s += (int)m64[(size_t)b * LL + k * 64 + lane];
  } else {                                  // int32
    const int* mi = (const int*)maskp;
#pragma unroll
    for (int k = 0; k < 16; ++k) s += mi[b * LL + k * 64 + lane];
  }
  const int len = wave_sum_i(s);            // uniform

  // ---- E column j in 52 named registers
#define EDECL(a, b_, c, d)                                   \
  float E##a  = jok ? __expf(trans[(a)*TT + j]) : 0.f;       \
  float E##b_ = jok ? __expf(trans[(b_)*TT + j]) : 0.f;      \
  float E##c  = jok ? __expf(trans[(c)*TT + j]) : 0.f;       \
  float E##d  = jok ? __expf(trans[(d)*TT + j]) : 0.f;
  EGROUPS(EDECL)

  const float tl = jok ? __expf(trans[j * TT + STOP_TAG]) : 0.f;

  const float* fp = feats + (size_t)b * LL * TT + j;
  float p = __expf(fp[0]) * E50;            // part0 = f0 + trans[START]
  float carry2 = 0.f;                       // log2 of accumulated renorms

#define ESTEP4(a, b_, c, d)                 \
  a0 = fmaf(rl(p, (a)), E##a, a0);          \
  a1 = fmaf(rl(p, (b_)), E##b_, a1);        \
  a2 = fmaf(rl(p, (c)), E##c, a2);          \
  a3 = fmaf(rl(p, (d)), E##d, a3);

#define CRF_STEP(FV)                        \
  {                                         \
    const float eft = __expf((FV)-6.0f);    \
    float a0 = 0.f, a1 = 0.f, a2 = 0.f, a3 = 0.f; \
    EGROUPS(ESTEP4)                         \
    p = ((a0 + a1) + (a2 + a3)) * eft;      \
  }

  // keep-alive pin: forces all 52 E values VGPR-resident here each chunk,
  // so remat/spill-reload inside the steps is never profitable.
#define EPIN(a, b_, c, d) \
  asm volatile("" : "+v"(E##a), "+v"(E##b_), "+v"(E##c), "+v"(E##d));

  const int nsteps = len - 1;               // steps t = 1 .. len-1
  const int nchunk = nsteps >> 3;
  const int ntail = nsteps & 7;

  float fb[8];                              // emissions for current 8 steps
#pragma unroll
  for (int k = 0; k < 8; ++k) fb[k] = fp[(size_t)(1 + k) * TT];  // len>=512

  int tbase = 1;
  for (int c = 0; c < nchunk; ++c) {
    EGROUPS(EPIN)
    float fn[8];                            // prefetch next chunk (~8 steps ahead)
#pragma unroll
    for (int k = 0; k < 8; ++k) {
      int tt = tbase + 8 + k;
      tt = tt < len ? tt : len - 1;         // clamp: harmless in-bounds load
      fn[k] = fp[(size_t)tt * TT];
    }
#pragma unroll
    for (int k = 0; k < 8; ++k) CRF_STEP(fb[k]);
    const float m = wave_max(p);            // renorm every 8 steps
    carry2 += __log2f(m);
    p *= __builtin_amdgcn_rcpf(m);
#pragma unroll
    for (int k = 0; k < 8; ++k) fb[k] = fn[k];
    tbase += 8;
  }
#pragma unroll
  for (int k = 0; k < 8; ++k)               // tail, statically indexed
    if (k < ntail) CRF_STEP(fb[k]);

  // forward score = log(sum p_i * e^trans[i,STOP]) + renorms + bias payback
  const float sfin = wave_sum(p * tl);
  const float fwd =
      (__log2f(sfin) + carry2) * 0.6931471805599453f + 6.0f * (float)(len - 1);

  // ---- gold score, lane-parallel over time
  const int* tgb = tags + b * LL;
  float g = 0.f;
  for (int base = 0; base < len; base += 64) {
    const int t = base + lane;
    if (t < len) {
      const int tag = tgb[t];
      const int prev = (t == 0) ? START_TAG : tgb[t - 1];
      g += feats[((size_t)b * LL + t) * TT + tag] + trans[prev * TT + tag];
    }
  }
  g = wave_sum(g);

  if (lane == 0) {
    g += trans[tgb[len - 1] * TT + STOP_TAG];
    res[b] = fwd - g;
  }
#undef CRF_STEP
#undef ESTEP4
#undef EDECL
#undef EPIN
}

__global__ __launch_bounds__(64) void crf_fin(const float* __restrict__ res,
                                              float* __restrict__ out) {
  float s = 0.f;
#pragma unroll
  for (int k = 0; k < 8; ++k) s += res[threadIdx.x + k * 64];
  s = wave_sum(s);
  if (threadIdx.x == 0) out[0] = s * (1.0f / (float)BB);
}

extern "C" void kernel_launch(void* const* d_in, const int* in_sizes, int n_in,
                              void* d_out, int out_size, void* d_ws, size_t ws_size,
                              hipStream_t stream) {
  const float* feats = (const float*)d_in[0];
  const float* trans = (const float*)d_in[1];
  const void* mask   = (const void*)d_in[2];
  const int* tags    = (const int*)d_in[3];

  float* res = (float*)d_ws;                // 512 per-batch results

  crf_main<<<BB, 64, 0, stream>>>(feats, trans, mask, tags, res);
  crf_fin<<<1, 64, 0, stream>>>(res, (float*)d_out);
}

// Round 5
// 355.341 us; speedup vs baseline: 1.0835x; 1.0439x over previous
//
#include <hip/hip_runtime.h>

#define BB 512
#define LL 1024
#define TT 52
#define START_TAG 50   // T-2
#define STOP_TAG  51   // T-1

__device__ __forceinline__ float rl(float v, int i) {
  return __uint_as_float(__builtin_amdgcn_readlane(__float_as_uint(v), (unsigned)i));
}
__device__ __forceinline__ float wave_max(float v) {
#pragma unroll
  for (int off = 32; off; off >>= 1) v = fmaxf(v, __shfl_xor(v, off, 64));
  return v;
}
__device__ __forceinline__ float wave_sum(float v) {
#pragma unroll
  for (int off = 32; off; off >>= 1) v += __shfl_xor(v, off, 64);
  return v;
}
__device__ __forceinline__ int wave_sum_i(int v) {
#pragma unroll
  for (int off = 32; off; off >>= 1) v += __shfl_xor(v, off, 64);
  return v;
}

// 13 groups of 4 state indices — used for E decls, readlanes, FMAs, pins.
#define EGROUPS(G)                                                      \
  G(0, 1, 2, 3) G(4, 5, 6, 7) G(8, 9, 10, 11) G(12, 13, 14, 15)        \
  G(16, 17, 18, 19) G(20, 21, 22, 23) G(24, 25, 26, 27)                \
  G(28, 29, 30, 31) G(32, 33, 34, 35) G(36, 37, 38, 39)                \
  G(40, 41, 42, 43) G(44, 45, 46, 47) G(48, 49, 50, 51)

// One wave per batch; lane j = tag state j.  Forward recursion in exp space
// with per-step bias e^-6 and renorm every 16 steps.  E in 52 named VGPRs
// (amdgpu_waves_per_eu(1,1) lifts the budget; R4 verified VGPR_Count=132).
// Each step: 52 readlanes -> uniform temps (SGPRs), sched_barrier, 52 FMAs —
// separates v_readlane SGPR-writes from their VALU readers (hazard stalls
// measured as ~580 vs ~216 cyc/step issue floor in R4).
__global__ __launch_bounds__(64)
__attribute__((amdgpu_waves_per_eu(1, 1)))
void crf_main(
    const float* __restrict__ feats, const float* __restrict__ trans,
    const void* __restrict__ maskp, const int* __restrict__ tags,
    float* __restrict__ res) {
  const int b = blockIdx.x;
  const int lane = threadIdx.x;
  const bool jok = lane < TT;
  const int j = jok ? lane : TT - 1;        // clamp keeps loads in-bounds

  // ---- per-block length from prefix mask (dtype sniffed from content:
  // len>=512 guarantees first elements true; u8->0x01010101, i32->1,1, i64->1,0)
  const unsigned* m32 = (const unsigned*)maskp;
  int s = 0;
  const unsigned v0 = m32[0];
  if (v0 == 0x01010101u) {                  // bool as bytes
    const uint4* mv = (const uint4*)maskp;  // row = 1024 B = 64 uint4
    uint4 x = mv[b * 64 + lane];
    s  = (int)(((x.x & 0x01010101u) * 0x01010101u) >> 24);
    s += (int)(((x.y & 0x01010101u) * 0x01010101u) >> 24);
    s += (int)(((x.z & 0x01010101u) * 0x01010101u) >> 24);
    s += (int)(((x.w & 0x01010101u) * 0x01010101u) >> 24);
  } else if (m32[1] == 0u) {                // int64
    const unsigned long long* m64 = (const unsigned long long*)maskp;
#pragma unroll
    for (int k = 0; k < 16; ++k) s += (int)m64[(size_t)b * LL + k * 64 + lane];
  } else {                                  // int32
    const int* mi = (const int*)maskp;
#pragma unroll
    for (int k = 0; k < 16; ++k) s += mi[b * LL + k * 64 + lane];
  }
  const int len = wave_sum_i(s);            // uniform

  // ---- E column j in 52 named registers
#define EDECL(a, b_, c, d)                                   \
  float E##a  = jok ? __expf(trans[(a)*TT + j]) : 0.f;       \
  float E##b_ = jok ? __expf(trans[(b_)*TT + j]) : 0.f;      \
  float E##c  = jok ? __expf(trans[(c)*TT + j]) : 0.f;       \
  float E##d  = jok ? __expf(trans[(d)*TT + j]) : 0.f;
  EGROUPS(EDECL)

  const float tl = jok ? __expf(trans[j * TT + STOP_TAG]) : 0.f;

  const float* fp = feats + (size_t)b * LL * TT + j;
  float p = __expf(fp[0]) * E50;            // part0 = f0 + trans[START]
  float carry2 = 0.f;                       // log2 of accumulated renorms

  // phase 1: broadcast all 52 p values to wave-uniform temps (SGPRs)
#define RLDECL(a, b_, c, d)                 \
  const float P##a  = rl(p, (a));           \
  const float P##b_ = rl(p, (b_));          \
  const float P##c  = rl(p, (c));           \
  const float P##d  = rl(p, (d));
  // phase 2: consume them — every FMA is far from its producing readlane
#define EFMA(a, b_, c, d)                   \
  a0 = fmaf(P##a, E##a, a0);                \
  a1 = fmaf(P##b_, E##b_, a1);              \
  a2 = fmaf(P##c, E##c, a2);                \
  a3 = fmaf(P##d, E##d, a3);

#define CRF_STEP(FV)                        \
  {                                         \
    const float eft = __expf((FV)-6.0f);    \
    EGROUPS(RLDECL)                         \
    __builtin_amdgcn_sched_barrier(0);      \
    float a0 = 0.f, a1 = 0.f, a2 = 0.f, a3 = 0.f; \
    EGROUPS(EFMA)                           \
    p = ((a0 + a1) + (a2 + a3)) * eft;      \
  }

  // keep-alive pin: E stays VGPR-resident across the chunk loop
#define EPIN(a, b_, c, d) \
  asm volatile("" : "+v"(E##a), "+v"(E##b_), "+v"(E##c), "+v"(E##d));

#define CH 16
  const int nsteps = len - 1;               // steps t = 1 .. len-1
  const int nchunk = nsteps / CH;
  const int ntail = nsteps % CH;

  float fb[CH];                             // emissions for current chunk
#pragma unroll
  for (int k = 0; k < CH; ++k) fb[k] = fp[(size_t)(1 + k) * TT];  // len>=512

  int tbase = 1;
  for (int c = 0; c < nchunk; ++c) {
    EGROUPS(EPIN)
    float fn[CH];                           // prefetch next chunk (~16 steps ahead)
#pragma unroll
    for (int k = 0; k < CH; ++k) {
      int tt = tbase + CH + k;
      tt = tt < len ? tt : len - 1;         // clamp: harmless in-bounds load
      fn[k] = fp[(size_t)tt * TT];
    }
#pragma unroll
    for (int k = 0; k < CH; ++k) CRF_STEP(fb[k]);
    const float m = wave_max(p);            // renorm every 16 steps
    carry2 += __log2f(m);
    p *= __builtin_amdgcn_rcpf(m);
#pragma unroll
    for (int k = 0; k < CH; ++k) fb[k] = fn[k];
    tbase += CH;
  }
#pragma unroll
  for (int k = 0; k < CH; ++k)              // tail, statically indexed
    if (k < ntail) CRF_STEP(fb[k]);

  // forward score = log(sum p_i * e^trans[i,STOP]) + renorms + bias payback
  const float sfin = wave_sum(p * tl);
  const float fwd =
      (__log2f(sfin) + carry2) * 0.6931471805599453f + 6.0f * (float)(len - 1);

  // ---- gold score, lane-parallel over time
  const int* tgb = tags + b * LL;
  float g = 0.f;
  for (int base = 0; base < len; base += 64) {
    const int t = base + lane;
    if (t < len) {
      const int tag = tgb[t];
      const int prev = (t == 0) ? START_TAG : tgb[t - 1];
      g += feats[((size_t)b * LL + t) * TT + tag] + trans[prev * TT + tag];
    }
  }
  g = wave_sum(g);

  if (lane == 0) {
    g += trans[tgb[len - 1] * TT + STOP_TAG];
    res[b] = fwd - g;
  }
#undef CRF_STEP
#undef EFMA
#undef RLDECL
#undef ESTEP4
#undef EDECL
#undef EPIN
}

__global__ __launch_bounds__(64) void crf_fin(const float* __restrict__ res,
                                              float* __restrict__ out) {
  float s = 0.f;
#pragma unroll
  for (int k = 0; k < 8; ++k) s += res[threadIdx.x + k * 64];
  s = wave_sum(s);
  if (threadIdx.x == 0) out[0] = s * (1.0f / (float)BB);
}

extern "C" void kernel_launch(void* const* d_in, const int* in_sizes, int n_in,
                              void* d_out, int out_size, void* d_ws, size_t ws_size,
                              hipStream_t stream) {
  const float* feats = (const float*)d_in[0];
  const float* trans = (const float*)d_in[1];
  const void* mask   = (const void*)d_in[2];
  const int* tags    = (const int*)d_in[3];

  float* res = (float*)d_ws;                // 512 per-batch results

  crf_main<<<BB, 64, 0, stream>>>(feats, trans, mask, tags, res);
  crf_fin<<<1, 64, 0, stream>>>(res, (float*)d_out);
}